// Round 15
// baseline (1364.158 us; speedup 1.0000x reference)
//
#include <hip/hip_runtime.h>

typedef unsigned long long u64;
typedef unsigned int u32;

#define TSTEPS 8192
#define NSEG   2048
#define DTC    0.025f

// Persistent single-wave halo decomposition (r9 geometry/math): 256 blocks x
// 64 lanes, 1 seg/lane. Owned lanes 28..35 (8 segs) valid for K=28 steps.
// Fence-free sync via (tag<<32|f32bits) relaxed agent-scope atomics.
// r15: phase-boundary reorder to minimize the spin's in-order vmcnt drain:
//   spin(p) -> dump(p-1 from LDS) -> prefetch stim(p+1) -> steps(p, VMEM-
//   free) -> publish(p+1).
// The poll now drains only the 4 publish stores; dump stores + stim loads
// retire under the 3.6k-cyc step loop. Double-buffered LDS output planes and
// stim register buffers.
#define KST    28
#define KTAIL  16
#define WAVE   64
#define COWN   8
#define NBLK   (NSEG / COWN)                 // 256
#define NPH    ((TSTEPS + KST - 1) / KST)    // 293 (292 full + 16-step tail)
#define JLO    KST                           // owned lanes [28, 36)

constexpr double L2E = 1.4426950408889634074;   // log2(e)

#define AM_A ((float)(-0.1 * L2E))              // em0 = exp2(AM_A*V) = e^{-0.1V}
#define CEM  0.018315638888734179f              // e^-4    -> am's exp
#define CEH  0.030197383422318501f              // e^-3.5  -> bh's exp
#define CEN  0.0040867714384640666f             // e^-5.5  -> an's exp
#define BM_A ((float)(-L2E / 18.0))
#define BM_B ((float)(2.0 - 65.0 * L2E / 18.0)) // bm = 4e^{-(V+65)/18}
#define QA   ((float)(-L2E / 80.0))
#define QB   ((float)(-65.0 * L2E / 80.0))      // q = e^{-(V+65)/80}; bn=q/8; ah=0.07q^4
#define CAH  0.2645751311064591f                // sqrt(0.07)

#define AL(p) __hip_atomic_load((p), __ATOMIC_RELAXED, __HIP_MEMORY_SCOPE_AGENT)
#define AS(p, v) __hip_atomic_store((p), (v), __ATOMIC_RELAXED, __HIP_MEMORY_SCOPE_AGENT)

__device__ __forceinline__ u64 pack_tag(float v, int tag) {
    return ((u64)(u32)tag << 32) | (u64)__float_as_uint(v);
}
__device__ __forceinline__ float lo_f(u64 w) { return __uint_as_float((u32)w); }
__device__ __forceinline__ float bperm(int addr, float v) {
    return __int_as_float(__builtin_amdgcn_ds_bpermute(addr, __float_as_int(v)));
}

// KS = steps this phase (consumes stC, writes LDS plane cur);
// KN = stim rows prefetched into stN for phase p+1;
// KP = rows of phase p-1 dumped from LDS plane prv (0 at p=0).
template <int KS, int KN, int KP>
__device__ __forceinline__ void run_phase(
    int p, int b, int j, int s, int sc,
    bool owned, int addrL, int addrR,
    float gna, float gk, float gl, float gax,
    const float* __restrict__ stim, u64* __restrict__ tstate,
    float* __restrict__ out_cur, float* __restrict__ out_volt,
    float2* cur, float2* prv, float (&stC)[KST], float (&stN)[KST],
    float& V, float& m, float& h, float& n, bool pub)
{
    const int t0 = p * KST;

    // ---- 1) spin: only the 4 publish stores are outstanding VMEM here;
    // dump/prefetch of the previous iteration retired under its step loop.
    const bool needLoad = (!owned) || (p == 0);
    const u64* sb = tstate + (size_t)(p & 1) * 4 * NSEG + sc;
    {
        u64 w0 = 0, w1 = 0, w2 = 0, w3 = 0;
        int ok;
        do {
            ok = 1;
            if (needLoad) {
                w0 = AL(sb);            w1 = AL(sb + NSEG);
                w2 = AL(sb + 2 * NSEG); w3 = AL(sb + 3 * NSEG);
                ok = (int)(w0 >> 32) >= p && (int)(w1 >> 32) >= p &&
                     (int)(w2 >> 32) >= p && (int)(w3 >> 32) >= p;
            }
        } while (!__all(ok));
        if (needLoad) {
            V = lo_f(w0); m = lo_f(w1); h = lo_f(w2); n = lo_f(w3);
        }
    }
    __builtin_amdgcn_sched_barrier(0);

    // ---- 2) dump phase p-1's outputs (LDS plane prv -> global); stores
    // retire under the step loop below, drained long before the next spin.
    if (KP > 0) {
        const int t0p = t0 - KST;
        const int sbase = b * COWN;
#pragma unroll
        for (int base = 0; base < KP * COWN; base += WAVE) {
            const int idx = base + j;
            if (idx < KP * COWN) {
                const float2 v = prv[idx];
                const size_t go = (size_t)(t0p + (idx >> 3)) * NSEG + sbase + (idx & 7);
                __builtin_nontemporal_store(v.x, out_cur + go);
                __builtin_nontemporal_store(v.y, out_volt + go);
            }
        }
    }

    // ---- 3) prefetch stim for phase p+1 (lands under the step loop)
    if (KN > 0) {
        const float* spn = stim + (size_t)(t0 + KST) * NSEG + sc;
#pragma unroll
        for (int u = 0; u < KN; ++u)
            stN[u] = spn[(size_t)u * NSEG];
    }
    __builtin_amdgcn_sched_barrier(0);

    // ---- 4) K steps (VMEM-free; r9 math verbatim). Outputs to LDS plane
    // cur, owned lanes only (conflict-free).
    float Vl = bperm(addrL, V);
    float Vr = bperm(addrR, V);
    const int jo = j - JLO;
#pragma unroll
    for (int k = 0; k < KS; ++k) {
        const float is = stC[k];
        const float ax = (Vl + Vr) - 2.0f * V;
        const float mc = __builtin_fmaf(gax, ax, is);     // mem_cur = i_ax + is
        const float m3 = m * m * m;
        const float n2 = n * n;
        const float i_ion = gna * m3 * h * (V - 50.0f)
                          + gk * (n2 * n2) * (V + 77.0f)
                          + gl * (V + 54.387f);
        const float dV = mc - i_ion;
        const float Vn = __builtin_fmaf(DTC, dV, V);
        const float VlN = bperm(addrL, Vn);               // fly under rate math
        const float VrN = bperm(addrR, Vn);

        if (owned) cur[k * COWN + jo] = make_float2(mc, V);

        // rates from old V: 3 exp2 + 3 rcp, short chains (r9 numerics)
        const float em0 = __builtin_amdgcn_exp2f(V * AM_A);
        const float am  = __builtin_fmaf(0.1f, V, 4.0f) *
                          __builtin_amdgcn_rcpf(__builtin_fmaf(-CEM, em0, 1.0f));
        const float an  = __builtin_fmaf(0.01f, V, 0.55f) *
                          __builtin_amdgcn_rcpf(__builtin_fmaf(-CEN, em0, 1.0f));
        const float bh  = __builtin_amdgcn_rcpf(__builtin_fmaf(CEH, em0, 1.0f));
        const float bm  = __builtin_amdgcn_exp2f(__builtin_fmaf(V, BM_A, BM_B));
        const float q   = __builtin_amdgcn_exp2f(__builtin_fmaf(V, QA, QB));
        const float tq  = CAH * (q * q);
        const float ah  = tq * tq;                        // 0.07 * q^4
        const float bn  = 0.125f * q;

        m = __builtin_fmaf(DTC, __builtin_fmaf(-(am + bm), m, am), m);
        h = __builtin_fmaf(DTC, __builtin_fmaf(-(ah + bh), h, ah), h);
        n = __builtin_fmaf(DTC, __builtin_fmaf(-(an + bn), n, an), n);
        V = Vn; Vl = VlN; Vr = VrN;
    }

    // ---- 5) publish (the only VMEM between here and the next spin)
    if (pub && owned) {
        u64* pb = tstate + (size_t)((p + 1) & 1) * 4 * NSEG + s;
        AS(pb,            pack_tag(V, p + 1));
        AS(pb + NSEG,     pack_tag(m, p + 1));
        AS(pb + 2 * NSEG, pack_tag(h, p + 1));
        AS(pb + 3 * NSEG, pack_tag(n, p + 1));
    }
}

__global__ __launch_bounds__(WAVE, 1) void hh_persist(
    const float* __restrict__ stim,
    const float* __restrict__ gna_p, const float* __restrict__ gk_p,
    const float* __restrict__ gl_p,  const float* __restrict__ gax_p,
    u64* __restrict__ tstate,        // 2 buffers x 4 comps x NSEG tagged words
    float* __restrict__ out_cur, float* __restrict__ out_volt,
    float* __restrict__ tail)
{
    const int j = threadIdx.x;
    const int b = blockIdx.x;
    const int s = b * COWN - KST + j;               // may be out of range (halo)
    const int sc = s < 0 ? 0 : (s > NSEG - 1 ? NSEG - 1 : s);
    const bool owned = (j >= JLO) && (j < JLO + COWN);

    // precomputed bpermute byte-addresses, sealed ends baked in (neighbor=
    // self). Wave-edge lanes read self: harmless, they're at cone distance K.
    const int jl = (s <= 0)        ? j : (j > 0  ? j - 1 : 0);
    const int jr = (s >= NSEG - 1) ? j : (j < 63 ? j + 1 : 63);
    const int addrL = jl * 4;
    const int addrR = jr * 4;

    const float gna = gna_p[sc], gk = gk_p[sc], gl = gl_p[sc], gax = gax_p[sc];

    __shared__ float2 pl0[KST * COWN], pl1[KST * COWN];   // 2 x 1792 B

    float V = 0.f, m = 0.f, h = 0.f, n = 0.f;
    float stA[KST], stB[KST];

    // prologue: prefetch phase 0's stim into stA (drains at the p=0 spin,
    // which waits on the init-kernel publication anyway)
#pragma unroll
    for (int u = 0; u < KST; ++u)
        stA[u] = stim[(size_t)u * NSEG + sc];
    __builtin_amdgcn_sched_barrier(0);

    // phase 0 (no previous dump), then pairs alternating buffers/planes
    run_phase<KST, KST, 0>(0, b, j, s, sc, owned, addrL, addrR,
                           gna, gk, gl, gax, stim, tstate, out_cur, out_volt,
                           pl0, pl1, stA, stB, V, m, h, n, true);
    for (int p = 1; p < 291; p += 2) {
        run_phase<KST, KST, KST>(p,     b, j, s, sc, owned, addrL, addrR,
                                 gna, gk, gl, gax, stim, tstate, out_cur, out_volt,
                                 pl1, pl0, stB, stA, V, m, h, n, true);
        run_phase<KST, KST, KST>(p + 1, b, j, s, sc, owned, addrL, addrR,
                                 gna, gk, gl, gax, stim, tstate, out_cur, out_volt,
                                 pl0, pl1, stA, stB, V, m, h, n, true);
    }
    // p=291 (prefetch only the 16-row tail), p=292 (tail steps, no publish)
    run_phase<KST, KTAIL, KST>(291, b, j, s, sc, owned, addrL, addrR,
                               gna, gk, gl, gax, stim, tstate, out_cur, out_volt,
                               pl1, pl0, stB, stA, V, m, h, n, true);
    run_phase<KTAIL, 0, KST>(292, b, j, s, sc, owned, addrL, addrR,
                             gna, gk, gl, gax, stim, tstate, out_cur, out_volt,
                             pl0, pl1, stA, stB, V, m, h, n, false);

    // final dump: phase 292's outputs (plane 0, 16 rows) + state tail
    {
        const int t0 = 292 * KST;
        const int sbase = b * COWN;
#pragma unroll
        for (int base = 0; base < KTAIL * COWN; base += WAVE) {
            const int idx = base + j;
            if (idx < KTAIL * COWN) {
                const float2 v = pl0[idx];
                const size_t go = (size_t)(t0 + (idx >> 3)) * NSEG + sbase + (idx & 7);
                __builtin_nontemporal_store(v.x, out_cur + go);
                __builtin_nontemporal_store(v.y, out_volt + go);
            }
        }
    }
    if (owned) {
        tail[s] = V; tail[NSEG + s] = m;
        tail[2 * NSEG + s] = h; tail[3 * NSEG + s] = n;
    }
}

__global__ void hh_init(const float* __restrict__ V0, const float* __restrict__ m0,
                        const float* __restrict__ h0, const float* __restrict__ n0,
                        u64* __restrict__ tstate)
{
    const int i = blockIdx.x * blockDim.x + threadIdx.x;
    if (i < NSEG) {
        // buffer 0 = publication for phase 0, tag 0
        tstate[i]            = pack_tag(V0[i], 0);
        tstate[NSEG + i]     = pack_tag(m0[i], 0);
        tstate[2 * NSEG + i] = pack_tag(h0[i], 0);
        tstate[3 * NSEG + i] = pack_tag(n0[i], 0);
        // buffer 1: invalid tag (replay determinism -- clear stale tags)
        u64* b1 = tstate + 4 * NSEG;
        const u64 inv = (u64)(u32)0x80000000u << 32;
        b1[i] = inv; b1[NSEG + i] = inv; b1[2 * NSEG + i] = inv; b1[3 * NSEG + i] = inv;
    }
}

extern "C" void kernel_launch(void* const* d_in, const int* in_sizes, int n_in,
                              void* d_out, int out_size, void* d_ws, size_t ws_size,
                              hipStream_t stream)
{
    const float* stim = (const float*)d_in[0];
    const float* V0   = (const float*)d_in[1];
    const float* m0   = (const float*)d_in[2];
    const float* h0   = (const float*)d_in[3];
    const float* n0   = (const float*)d_in[4];
    const float* gna  = (const float*)d_in[5];
    const float* gk   = (const float*)d_in[6];
    const float* gl   = (const float*)d_in[7];
    const float* gax  = (const float*)d_in[8];

    float* out      = (float*)d_out;
    float* out_cur  = out;
    float* out_volt = out + (size_t)TSTEPS * NSEG;
    float* tail     = out + 2 * (size_t)TSTEPS * NSEG;   // Vf, mf, hf, nf

    u64* tstate = (u64*)d_ws;    // 2 * 4 * NSEG tagged words = 128 KiB

    hipLaunchKernelGGL(hh_init, dim3(8), dim3(256), 0, stream,
                       V0, m0, h0, n0, tstate);
    hipLaunchKernelGGL(hh_persist, dim3(NBLK), dim3(WAVE), 0, stream,
                       stim, gna, gk, gl, gax, tstate,
                       out_cur, out_volt, tail);
}

// Round 16
// 1164.373 us; speedup vs baseline: 1.1716x; 1.1716x over previous
//
#include <hip/hip_runtime.h>

typedef unsigned long long u64;
typedef unsigned int u32;

#define TSTEPS 8192
#define NSEG   2048
#define DTC    0.025f

// Persistent single-wave halo decomposition (r9 structure, verbatim): 256
// blocks x 64 lanes, 1 seg/lane. Owned lanes 28..35 (8 segs) valid for K=28
// steps. Fence-free sync via (tag<<32|f32bits) relaxed agent-scope atomics.
// r16 = r9 + ONE change: rate software-pipelining. Rates for step k+1 are
// computed from Vn during step k (filling the bperm DS window); step k's
// gate updates consume rates carried from step k-1. The V->exp2->rcp->rate->
// gate->i_ion->V chain now spans TWO steps. Numerically identical: same
// expressions, same inputs, earlier schedule.
#define KST    28
#define KTAIL  16
#define WAVE   64
#define COWN   8
#define NBLK   (NSEG / COWN)                 // 256
#define NPH    ((TSTEPS + KST - 1) / KST)    // 293 (292 full + 16-step tail)
#define JLO    KST                           // owned lanes [28, 36)
#define LDP    66                            // LDS row stride in float2s

constexpr double L2E = 1.4426950408889634074;   // log2(e)

#define AM_A ((float)(-0.1 * L2E))              // em0 = exp2(AM_A*V) = e^{-0.1V}
#define CEM  0.018315638888734179f              // e^-4    -> am's exp
#define CEH  0.030197383422318501f              // e^-3.5  -> bh's exp
#define CEN  0.0040867714384640666f             // e^-5.5  -> an's exp
#define BM_A ((float)(-L2E / 18.0))
#define BM_B ((float)(2.0 - 65.0 * L2E / 18.0)) // bm = 4e^{-(V+65)/18}
#define QA   ((float)(-L2E / 80.0))
#define QB   ((float)(-65.0 * L2E / 80.0))      // q = e^{-(V+65)/80}; bn=q/8; ah=0.07q^4
#define CAH  0.2645751311064591f                // sqrt(0.07)

#define AL(p) __hip_atomic_load((p), __ATOMIC_RELAXED, __HIP_MEMORY_SCOPE_AGENT)
#define AS(p, v) __hip_atomic_store((p), (v), __ATOMIC_RELAXED, __HIP_MEMORY_SCOPE_AGENT)

__device__ __forceinline__ u64 pack_tag(float v, int tag) {
    return ((u64)(u32)tag << 32) | (u64)__float_as_uint(v);
}
__device__ __forceinline__ float lo_f(u64 w) { return __uint_as_float((u32)w); }
__device__ __forceinline__ float bperm(int addr, float v) {
    return __int_as_float(__builtin_amdgcn_ds_bpermute(addr, __float_as_int(v)));
}

// rates from a voltage value (r9 numerics, verbatim)
__device__ __forceinline__ void rates(float V, float& am, float& bm,
                                      float& ah, float& bh,
                                      float& an, float& bn)
{
    const float em0 = __builtin_amdgcn_exp2f(V * AM_A);
    am = __builtin_fmaf(0.1f, V, 4.0f) *
         __builtin_amdgcn_rcpf(__builtin_fmaf(-CEM, em0, 1.0f));
    an = __builtin_fmaf(0.01f, V, 0.55f) *
         __builtin_amdgcn_rcpf(__builtin_fmaf(-CEN, em0, 1.0f));
    bh = __builtin_amdgcn_rcpf(__builtin_fmaf(CEH, em0, 1.0f));
    bm = __builtin_amdgcn_exp2f(__builtin_fmaf(V, BM_A, BM_B));
    const float q = __builtin_amdgcn_exp2f(__builtin_fmaf(V, QA, QB));
    const float tq = CAH * (q * q);
    ah = tq * tq;                               // 0.07 * q^4
    bn = 0.125f * q;
}

template <int KS>
__device__ __forceinline__ void run_phase(
    int p, int b, int j, int s, int sc,
    bool owned, int addrL, int addrR,
    float gna, float gk, float gl, float gax,
    const float* __restrict__ stim, u64* __restrict__ tstate,
    float* __restrict__ out_cur, float* __restrict__ out_volt,
    float* lds, float& V, float& m, float& h, float& n, bool pub)
{
    const int t0 = p * KST;
    const float* sp = stim + (size_t)t0 * NSEG + sc;

    // issue ALL stim loads for this phase, pinned before the spin
    float st[KS];
#pragma unroll
    for (int k = 0; k < KS; ++k)
        st[k] = sp[(size_t)k * NSEG];
    __builtin_amdgcn_sched_barrier(0);

    // halo lanes (and everyone at p=0) spin on their own slot's 4 tagged
    // words; owned lanes keep exact state in registers across phases
    const bool needLoad = (!owned) || (p == 0);
    const u64* sb = tstate + (size_t)(p & 1) * 4 * NSEG + sc;
    {
        u64 w0 = 0, w1 = 0, w2 = 0, w3 = 0;
        int ok;
        do {
            ok = 1;
            if (needLoad) {
                w0 = AL(sb);            w1 = AL(sb + NSEG);
                w2 = AL(sb + 2 * NSEG); w3 = AL(sb + 3 * NSEG);
                ok = (int)(w0 >> 32) >= p && (int)(w1 >> 32) >= p &&
                     (int)(w2 >> 32) >= p && (int)(w3 >> 32) >= p;
            }
        } while (!__all(ok));
        if (needLoad) {
            V = lo_f(w0); m = lo_f(w1); h = lo_f(w2); n = lo_f(w3);
        }
    }

    // prologue: shuffles for step 0 + rates(V(0)) (fills the DS window)
    float Vl = bperm(addrL, V);
    float Vr = bperm(addrR, V);
    float am, bm, ah, bh, an, bn;
    rates(V, am, bm, ah, bh, an, bn);

    // K steps, rate-pipelined: step k consumes rates(V(k)) carried in;
    // computes V(k+1), issues its bperms, then computes rates(V(k+1)) while
    // the DS op flies; gate updates use the carried rates.
    float2* ld2 = (float2*)lds;
#pragma unroll
    for (int k = 0; k < KS; ++k) {
        const float is = st[k];
        const float ax = (Vl + Vr) - 2.0f * V;
        const float mc = __builtin_fmaf(gax, ax, is);     // mem_cur = i_ax + is
        const float m3 = m * m * m;
        const float n2 = n * n;
        const float i_ion = gna * m3 * h * (V - 50.0f)
                          + gk * (n2 * n2) * (V + 77.0f)
                          + gl * (V + 54.387f);
        const float dV = mc - i_ion;
        const float Vn = __builtin_fmaf(DTC, dV, V);
        const float VlN = bperm(addrL, Vn);               // fly under the rest
        const float VrN = bperm(addrR, Vn);

        ld2[k * LDP + j] = make_float2(mc, V);            // buffered output

        // next step's rates from Vn (off the per-step critical path)
        float amN, bmN, ahN, bhN, anN, bnN;
        rates(Vn, amN, bmN, ahN, bhN, anN, bnN);

        // gate updates with the CARRIED rates (= rates of V(k))
        m = __builtin_fmaf(DTC, __builtin_fmaf(-(am + bm), m, am), m);
        h = __builtin_fmaf(DTC, __builtin_fmaf(-(ah + bh), h, ah), h);
        n = __builtin_fmaf(DTC, __builtin_fmaf(-(an + bn), n, an), n);

        V = Vn; Vl = VlN; Vr = VrN;
        am = amN; bm = bmN; ah = ahN; bh = bhN; an = anN; bn = bnN;
    }

    // publish FIRST (MALL visibility latency hides under the dump below)
    if (pub && owned) {
        u64* pb = tstate + (size_t)((p + 1) & 1) * 4 * NSEG + s;
        AS(pb,            pack_tag(V, p + 1));
        AS(pb + NSEG,     pack_tag(m, p + 1));
        AS(pb + 2 * NSEG, pack_tag(h, p + 1));
        AS(pb + 3 * NSEG, pack_tag(n, p + 1));
    }
    __builtin_amdgcn_sched_barrier(0);

    // bulk-dump owned columns LDS -> global, all 64 lanes coalesced
    const int sbase = b * COWN;
#pragma unroll
    for (int base = 0; base < KS * COWN; base += WAVE) {
        const int idx = base + j;
        if (idx < KS * COWN) {
            const int t  = idx >> 3;
            const int sl = idx & 7;
            const float* lp = lds + (size_t)(t * LDP + JLO + sl) * 2;
            const size_t go = (size_t)(t0 + t) * NSEG + (sbase + sl);
            __builtin_nontemporal_store(lp[0], out_cur + go);
            __builtin_nontemporal_store(lp[1], out_volt + go);
        }
    }
}

__global__ __launch_bounds__(WAVE, 1) void hh_persist(
    const float* __restrict__ stim,
    const float* __restrict__ gna_p, const float* __restrict__ gk_p,
    const float* __restrict__ gl_p,  const float* __restrict__ gax_p,
    u64* __restrict__ tstate,        // 2 buffers x 4 comps x NSEG tagged words
    float* __restrict__ out_cur, float* __restrict__ out_volt,
    float* __restrict__ tail)
{
    const int j = threadIdx.x;
    const int b = blockIdx.x;
    const int s = b * COWN - KST + j;               // may be out of range (halo)
    const int sc = s < 0 ? 0 : (s > NSEG - 1 ? NSEG - 1 : s);
    const bool owned = (j >= JLO) && (j < JLO + COWN);

    // precomputed bpermute byte-addresses, sealed ends baked in (neighbor=
    // self). Wave-edge lanes read self: harmless, they're at cone distance K.
    const int jl = (s <= 0)        ? j : (j > 0  ? j - 1 : 0);
    const int jr = (s >= NSEG - 1) ? j : (j < 63 ? j + 1 : 63);
    const int addrL = jl * 4;
    const int addrR = jr * 4;

    const float gna = gna_p[sc], gk = gk_p[sc], gl = gl_p[sc], gax = gax_p[sc];

    __shared__ float lds[KST * LDP * 2];

    float V = 0.f, m = 0.f, h = 0.f, n = 0.f;

    for (int p = 0; p < NPH - 1; ++p)
        run_phase<KST>(p, b, j, s, sc, owned, addrL, addrR, gna, gk, gl, gax,
                       stim, tstate, out_cur, out_volt, lds, V, m, h, n, true);
    run_phase<KTAIL>(NPH - 1, b, j, s, sc, owned, addrL, addrR, gna, gk, gl, gax,
                     stim, tstate, out_cur, out_volt, lds, V, m, h, n, false);

    if (owned) {
        tail[s] = V; tail[NSEG + s] = m;
        tail[2 * NSEG + s] = h; tail[3 * NSEG + s] = n;
    }
}

__global__ void hh_init(const float* __restrict__ V0, const float* __restrict__ m0,
                        const float* __restrict__ h0, const float* __restrict__ n0,
                        u64* __restrict__ tstate)
{
    const int i = blockIdx.x * blockDim.x + threadIdx.x;
    if (i < NSEG) {
        // buffer 0 = publication for phase 0, tag 0
        tstate[i]            = pack_tag(V0[i], 0);
        tstate[NSEG + i]     = pack_tag(m0[i], 0);
        tstate[2 * NSEG + i] = pack_tag(h0[i], 0);
        tstate[3 * NSEG + i] = pack_tag(n0[i], 0);
        // buffer 1: invalid tag (replay determinism -- clear stale tags)
        u64* b1 = tstate + 4 * NSEG;
        const u64 inv = (u64)(u32)0x80000000u << 32;
        b1[i] = inv; b1[NSEG + i] = inv; b1[2 * NSEG + i] = inv; b1[3 * NSEG + i] = inv;
    }
}

extern "C" void kernel_launch(void* const* d_in, const int* in_sizes, int n_in,
                              void* d_out, int out_size, void* d_ws, size_t ws_size,
                              hipStream_t stream)
{
    const float* stim = (const float*)d_in[0];
    const float* V0   = (const float*)d_in[1];
    const float* m0   = (const float*)d_in[2];
    const float* h0   = (const float*)d_in[3];
    const float* n0   = (const float*)d_in[4];
    const float* gna  = (const float*)d_in[5];
    const float* gk   = (const float*)d_in[6];
    const float* gl   = (const float*)d_in[7];
    const float* gax  = (const float*)d_in[8];

    float* out      = (float*)d_out;
    float* out_cur  = out;
    float* out_volt = out + (size_t)TSTEPS * NSEG;
    float* tail     = out + 2 * (size_t)TSTEPS * NSEG;   // Vf, mf, hf, nf

    u64* tstate = (u64*)d_ws;    // 2 * 4 * NSEG tagged words = 128 KiB

    hipLaunchKernelGGL(hh_init, dim3(8), dim3(256), 0, stream,
                       V0, m0, h0, n0, tstate);
    hipLaunchKernelGGL(hh_persist, dim3(NBLK), dim3(WAVE), 0, stream,
                       stim, gna, gk, gl, gax, tstate,
                       out_cur, out_volt, tail);
}